// Round 5
// baseline (325.325 us; speedup 1.0000x reference)
//
#include <hip/hip_runtime.h>
#include <hip/hip_bf16.h>

// Problem: B=4, S=2048, H=1024, NH=16, DK=64. fp32 I/O.
// R13: recombine proven pieces. R12 showed attn is LATENCY-bound (CU-level
// pipes ~12% busy/SIMD; serial QK^T->exp->PV chain, only 16 waves/CU at
// 256-thr blocks), and that K=16 MFMAs waste the matrix pipe (MfmaUtil
// +52% at constant FLOPs). So attn returns to the 512-thr / 8-wave / 16
// q-rows-per-wave shape (32 waves/CU) with the R11 Ps-LDS all-K=32
// dataflow, keeping the two verified wins:
//  - raw v_exp_f32 softmax (R11, -30us)
//  - bijective XCD swizzle (R12: FETCH 139MB -> 25MB)
// GEMMs / converters unchanged.

typedef __hip_bfloat16 bf16;
typedef __attribute__((ext_vector_type(8))) short bf16x8;  // 8 bf16 = 4 VGPRs
typedef __attribute__((ext_vector_type(4))) float f32x4;

#define B_   4
#define S_   2048
#define H_   1024
#define NH_  16
#define DK_  64
#define M_   8192   // B_*S_
#define N1_  3072
#define K_   1024

#define SCALE_Q 0.18033688f   // 0.125 * log2(e): softmax in exp2 domain

typedef const __attribute__((address_space(1))) void* gas_t;
typedef __attribute__((address_space(3))) void* las_t;
#define G2L16(g, l) __builtin_amdgcn_global_load_lds((gas_t)(g), (las_t)(l), 16, 0, 0)

#if __has_builtin(__builtin_amdgcn_exp2f)
#define EX2(x) __builtin_amdgcn_exp2f(x)
#else
#define EX2(x) exp2f(x)
#endif

__device__ __forceinline__ float b2f(bf16 v) { return __bfloat162float(v); }

// pack two fp32 -> two bf16 (RNE, finite inputs), 3 int ops + merge
__device__ __forceinline__ unsigned pk2(float a, float b) {
    unsigned ua = __float_as_uint(a);
    unsigned ub = __float_as_uint(b);
    ua += 0x7FFFu + ((ua >> 16) & 1u);
    ub += 0x7FFFu + ((ub >> 16) & 1u);
    return (ua >> 16) | (ub & 0xFFFF0000u);
}

// ---------------------------------------------------------------------------
// K-1: X fp32 -> bf16 (one-shot; removes cvt from the qkv K-loop)
// ---------------------------------------------------------------------------
__global__ __launch_bounds__(256) void conv_x(const float* __restrict__ X,
                                              bf16* __restrict__ Xb)
{
    size_t i = ((size_t)blockIdx.x * 256 + threadIdx.x) * 8;
    float4 lo = *(const float4*)&X[i];
    float4 hi = *(const float4*)&X[i + 4];
    uint4 u;
    u.x = pk2(lo.x, lo.y); u.y = pk2(lo.z, lo.w);
    u.z = pk2(hi.x, hi.y); u.w = pk2(hi.z, hi.w);
    *(uint4*)&Xb[i] = u;
}

// ---------------------------------------------------------------------------
// K0: convert + transpose weights: W [K][N] fp32 -> WT [N][K] bf16.
// ---------------------------------------------------------------------------
__global__ __launch_bounds__(256) void conv_wT(const float* __restrict__ W,
                                               bf16* __restrict__ WT,
                                               int Kdim, int Ndim)
{
    __shared__ bf16 T[64][72];
    const int tid = threadIdx.x;
    const int n0 = blockIdx.x * 64, k0 = blockIdx.y * 64;
    const int kr = tid >> 4, nc = (tid & 15) * 4;
    #pragma unroll
    for (int p = 0; p < 4; ++p) {
        float4 v = *(const float4*)&W[(size_t)(k0 + kr + p * 16) * Ndim + n0 + nc];
        T[nc + 0][kr + p * 16] = __float2bfloat16(v.x);
        T[nc + 1][kr + p * 16] = __float2bfloat16(v.y);
        T[nc + 2][kr + p * 16] = __float2bfloat16(v.z);
        T[nc + 3][kr + p * 16] = __float2bfloat16(v.w);
    }
    __syncthreads();
    const int nr = tid >> 2, kc = (tid & 3) * 16;
    *(bf16x8*)&WT[(size_t)(n0 + nr) * Kdim + k0 + kc]     = *(const bf16x8*)&T[nr][kc];
    *(bf16x8*)&WT[(size_t)(n0 + nr) * Kdim + k0 + kc + 8] = *(const bf16x8*)&T[nr][kc + 8];
}

// ---------------------------------------------------------------------------
// qkv epilogue shared by both variants
// ---------------------------------------------------------------------------
__device__ __forceinline__ void qkv_epilogue(
    const f32x4 acc[4][4], const float* __restrict__ B1,
    bf16* __restrict__ Qp, bf16* __restrict__ Kp, bf16* __restrict__ Vt,
    int n0, int m0, int wm, int wn, int quad, int col)
{
    const int which = n0 >> 10;          // 0=q 1=k 2=v
    const int bb = m0 >> 11;
    if (which == 2) {
        #pragma unroll
        for (int i = 0; i < 4; ++i) {
            int s = (m0 & (S_ - 1)) + wm * 64 + i * 16 + quad * 4;
            #pragma unroll
            for (int j = 0; j < 4; ++j) {
                int n = n0 + wn * 64 + j * 16 + col;
                int h = (n >> 6) & 15, d = n & 63;
                float bv = B1[n];
                uint2 t;
                t.x = pk2(acc[i][j][0] + bv, acc[i][j][1] + bv);
                t.y = pk2(acc[i][j][2] + bv, acc[i][j][3] + bv);
                *(uint2*)&Vt[(((size_t)(bb * NH_ + h)) * DK_ + d) * S_ + s] = t;
            }
        }
    } else {
        bf16* dst = which ? Kp : Qp;
        const float sc = which ? 1.0f : SCALE_Q;
        #pragma unroll
        for (int i = 0; i < 4; ++i) {
            #pragma unroll
            for (int r = 0; r < 4; ++r) {
                int s = (m0 & (S_ - 1)) + wm * 64 + i * 16 + quad * 4 + r;
                #pragma unroll
                for (int j = 0; j < 4; ++j) {
                    int n = n0 + wn * 64 + j * 16 + col;
                    int h = (n >> 6) & 15, d = n & 63;
                    dst[(((size_t)(bb * NH_ + h)) * S_ + s) * DK_ + d] =
                        __float2bfloat16((acc[i][j][r] + B1[n]) * sc);
                }
            }
        }
    }
}

// ---------------------------------------------------------------------------
// K1-fast: qkv = Xbf @ W1 + b1, pure m97 (G2L16 both operands).
// ---------------------------------------------------------------------------
__global__ __launch_bounds__(256) void gemm_qkv_mfma2(
    const bf16* __restrict__ Xb, const bf16* __restrict__ W1T,
    const float* __restrict__ B1,
    bf16* __restrict__ Qp, bf16* __restrict__ Kp, bf16* __restrict__ Vt)
{
    __shared__ bf16 As[128 * 32];
    __shared__ bf16 Bs[128 * 32];

    const int tid = threadIdx.x;
    const int lane = tid & 63, wv = tid >> 6;
    const int col = lane & 15, quad = lane >> 4;
    const int wm = wv >> 1, wn = wv & 1;
    const int n0 = blockIdx.x * 128, m0 = blockIdx.y * 128;

    f32x4 acc[4][4] = {};

    const bf16* Ag = Xb  + (size_t)m0 * K_;
    const bf16* Bg = W1T + (size_t)n0 * K_;

    for (int k0 = 0; k0 < K_; k0 += 32) {
        #pragma unroll
        for (int h = 0; h < 2; ++h) {
            int idx = tid + h * 256;
            int row = idx >> 2, c = (idx & 3) * 8;
            G2L16(Ag + (size_t)row * K_ + k0 + c, As + (size_t)idx * 8);
            G2L16(Bg + (size_t)row * K_ + k0 + c, Bs + (size_t)idx * 8);
        }
        __syncthreads();

        bf16x8 af[4], bfr[4];
        #pragma unroll
        for (int i = 0; i < 4; ++i)
            af[i] = *(const bf16x8*)&As[(wm * 64 + i * 16 + col) * 32 + quad * 8];
        #pragma unroll
        for (int j = 0; j < 4; ++j)
            bfr[j] = *(const bf16x8*)&Bs[(wn * 64 + j * 16 + col) * 32 + quad * 8];

        #pragma unroll
        for (int i = 0; i < 4; ++i)
            #pragma unroll
            for (int j = 0; j < 4; ++j)
                acc[i][j] = __builtin_amdgcn_mfma_f32_16x16x32_bf16(af[i], bfr[j], acc[i][j], 0, 0, 0);
        __syncthreads();
    }
    qkv_epilogue(acc, B1, Qp, Kp, Vt, n0, m0, wm, wn, quad, col);
}

// ---------------------------------------------------------------------------
// K1-fallback: qkv with in-loop fp32->bf16 A conversion.
// ---------------------------------------------------------------------------
__global__ __launch_bounds__(256) void gemm_qkv_mfma(
    const float* __restrict__ X, const bf16* __restrict__ W1T,
    const float* __restrict__ B1,
    bf16* __restrict__ Qp, bf16* __restrict__ Kp, bf16* __restrict__ Vt)
{
    __shared__ bf16 As[128 * 32];
    __shared__ bf16 Bs[128 * 32];

    const int tid = threadIdx.x;
    const int lane = tid & 63, wv = tid >> 6;
    const int col = lane & 15, quad = lane >> 4;
    const int wm = wv >> 1, wn = wv & 1;
    const int n0 = blockIdx.x * 128, m0 = blockIdx.y * 128;

    f32x4 acc[4][4] = {};

    const float* Ag = X   + (size_t)m0 * K_;
    const bf16*  Bg = W1T + (size_t)n0 * K_;

    for (int k0 = 0; k0 < K_; k0 += 32) {
        #pragma unroll
        for (int h = 0; h < 2; ++h) {
            int idx = tid + h * 256;
            int row = idx >> 2, c = (idx & 3) * 8;
            G2L16(Bg + (size_t)row * K_ + k0 + c, Bs + (size_t)idx * 8);
        }
        #pragma unroll
        for (int h = 0; h < 2; ++h) {
            int idx = tid + h * 256;
            int row = idx >> 2, c = (idx & 3) * 8;
            float4 lo = *(const float4*)&Ag[(size_t)row * K_ + k0 + c];
            float4 hi = *(const float4*)&Ag[(size_t)row * K_ + k0 + c + 4];
            uint4 u;
            u.x = pk2(lo.x, lo.y); u.y = pk2(lo.z, lo.w);
            u.z = pk2(hi.x, hi.y); u.w = pk2(hi.z, hi.w);
            *(uint4*)&As[(size_t)idx * 8] = u;
        }
        __syncthreads();

        bf16x8 af[4], bfr[4];
        #pragma unroll
        for (int i = 0; i < 4; ++i)
            af[i] = *(const bf16x8*)&As[(wm * 64 + i * 16 + col) * 32 + quad * 8];
        #pragma unroll
        for (int j = 0; j < 4; ++j)
            bfr[j] = *(const bf16x8*)&Bs[(wn * 64 + j * 16 + col) * 32 + quad * 8];

        #pragma unroll
        for (int i = 0; i < 4; ++i)
            #pragma unroll
            for (int j = 0; j < 4; ++j)
                acc[i][j] = __builtin_amdgcn_mfma_f32_16x16x32_bf16(af[i], bfr[j], acc[i][j], 0, 0, 0);
        __syncthreads();
    }
    qkv_epilogue(acc, B1, Qp, Kp, Vt, n0, m0, wm, wn, quad, col);
}

// ---------------------------------------------------------------------------
// K2: transposed-dataflow MFMA flash attention.
// Block = 512 threads (8 waves), 128 q-rows; wave owns 16 rows (r = col).
//   S^T = K*Q^T  (A = Ks rows, B = q-frags)  -> C-layout: col=r, row=c-offset
//   P = exp2(S^T) via raw v_exp_f32, stored k-contiguous: 4x ds_write_b64
//   O^T = Vt*P^T (A = Vs rows, B = Ps b128) -> ctx written as 4x 8B stores
//   l = ones*P^T on the MFMA pipe, col-indexed for the epilogue.
// 512-thr / 36.9KB LDS -> 4 blk x 8 waves = 32 waves/CU (latency-bound
// kernel: R12 showed pipes ~12%/SIMD busy; parallelism is the lever).
// Bijective XCD swizzle: all 16 q-tiles of a bh on one XCD (K/V L2-resident;
// R12 measured FETCH 139MB -> 25MB).
// ---------------------------------------------------------------------------
__global__ __launch_bounds__(512, 8) void attn_mfma(
    const bf16* __restrict__ Q, const bf16* __restrict__ K,
    const bf16* __restrict__ Vt, bf16* __restrict__ CTX)
{
    __shared__ bf16 Ks[64][72];      // [c][d]
    __shared__ bf16 Vs[64][72];      // [d][c]
    __shared__ bf16 Ps[8][16][72];   // per-wave P [r][c]

    const int tid  = threadIdx.x;
    const int wv   = tid >> 6;       // 0..7
    const int lane = tid & 63;
    const int col  = lane & 15;
    const int quad = lane >> 4;

    // bijective XCD swizzle: dispatch order round-robins lid%8 across XCDs;
    // give XCD x the contiguous vid range [x*128, (x+1)*128) = bh 8x..8x+7.
    const int lid = blockIdx.x + (blockIdx.y << 4);    // gridDim.x == 16
    const int vid = (lid & 7) * 128 + (lid >> 3);
    const int bh = vid >> 4;
    const int q0 = (vid & 15) * 128;

    const bf16* Qg  = Q  + (size_t)bh * S_ * DK_;
    const bf16* Kg  = K  + (size_t)bh * S_ * DK_;
    const bf16* Vtg = Vt + (size_t)bh * DK_ * S_;

    const short oneb = (short)0x3F80;
    const bf16x8 ones = {oneb, oneb, oneb, oneb, oneb, oneb, oneb, oneb};

    // Q fragments (used as B operand): lane(col) holds q-row q0+wv*16+col
    const int qrow = q0 + wv * 16 + col;
    bf16x8 qf[2];
    qf[0] = *(const bf16x8*)&Qg[(size_t)qrow * DK_ + quad * 8];
    qf[1] = *(const bf16x8*)&Qg[(size_t)qrow * DK_ + 32 + quad * 8];

    f32x4 o[4] = {};                      // O^T, d-subtiles
    f32x4 l_acc = {0.f, 0.f, 0.f, 0.f};   // row sums, col-indexed

    const int sr = tid >> 3;          // staging row 0..63 (512 threads)
    const int e0 = (tid & 7) * 8;

    // prefetch tile 0
    bf16x8 kreg = *(const bf16x8*)&Kg[(size_t)sr * DK_ + e0];
    bf16x8 vreg = *(const bf16x8*)&Vtg[(size_t)sr * S_ + e0];

    for (int kt = 0; kt < S_ / 64; ++kt) {
        *(bf16x8*)&Ks[sr][e0] = kreg;
        *(bf16x8*)&Vs[sr][e0] = vreg;
        __syncthreads();

        if (kt + 1 < S_ / 64) {
            kreg = *(const bf16x8*)&Kg[(size_t)((kt + 1) * 64 + sr) * DK_ + e0];
            vreg = *(const bf16x8*)&Vtg[(size_t)sr * S_ + (kt + 1) * 64 + e0];
        }

        // S^T = K Q^T, then p=exp2 packed straight to Ps (4x b64 per wave)
        #pragma unroll
        for (int cs = 0; cs < 4; ++cs) {
            const bf16* kb = &Ks[cs * 16 + col][0];
            f32x4 a = {0.f, 0.f, 0.f, 0.f};
            a = __builtin_amdgcn_mfma_f32_16x16x32_bf16(*(const bf16x8*)&kb[quad * 8],      qf[0], a, 0, 0, 0);
            a = __builtin_amdgcn_mfma_f32_16x16x32_bf16(*(const bf16x8*)&kb[32 + quad * 8], qf[1], a, 0, 0, 0);
            uint2 p;
            p.x = pk2(EX2(a[0]), EX2(a[1]));
            p.y = pk2(EX2(a[2]), EX2(a[3]));
            *(uint2*)&Ps[wv][col][cs * 16 + quad * 4] = p;
        }

        // read P as B-frags (same wave wrote it; per-wave buffer, no barrier)
        bf16x8 pf0 = *(const bf16x8*)&Ps[wv][col][quad * 8];
        bf16x8 pf1 = *(const bf16x8*)&Ps[wv][col][32 + quad * 8];

        // l += 1^T P (matrix pipe; every reg holds l[col])
        l_acc = __builtin_amdgcn_mfma_f32_16x16x32_bf16(ones, pf0, l_acc, 0, 0, 0);
        l_acc = __builtin_amdgcn_mfma_f32_16x16x32_bf16(ones, pf1, l_acc, 0, 0, 0);

        // O^T += Vt P^T
        #pragma unroll
        for (int ds = 0; ds < 4; ++ds) {
            const bf16* vb = &Vs[ds * 16 + col][0];
            o[ds] = __builtin_amdgcn_mfma_f32_16x16x32_bf16(*(const bf16x8*)&vb[quad * 8],      pf0, o[ds], 0, 0, 0);
            o[ds] = __builtin_amdgcn_mfma_f32_16x16x32_bf16(*(const bf16x8*)&vb[32 + quad * 8], pf1, o[ds], 0, 0, 0);
        }
        __syncthreads();
    }

    // epilogue: O^T C-layout -> 4 contiguous d per lane -> packed 8B stores
    const int b = bh >> 4, h = bh & 15;
    const float inv = 1.f / l_acc[0];
    const int srow = q0 + wv * 16 + col;
    bf16* crow = CTX + ((size_t)(b * S_ + srow)) * H_ + h * DK_;
    #pragma unroll
    for (int ds = 0; ds < 4; ++ds) {
        uint2 t;
        t.x = pk2(o[ds][0] * inv, o[ds][1] * inv);
        t.y = pk2(o[ds][2] * inv, o[ds][3] * inv);
        *(uint2*)&crow[ds * 16 + quad * 4] = t;
    }
}

// ---------------------------------------------------------------------------
// K3: out = ctx @ W2 + b2 (MFMA).
// ---------------------------------------------------------------------------
__global__ __launch_bounds__(256) void gemm_out_mfma(
    const bf16* __restrict__ Cx, const bf16* __restrict__ W2T,
    const float* __restrict__ B2, float* __restrict__ OUT)
{
    __shared__ bf16 As[128 * 32];
    __shared__ bf16 Bs[128 * 32];

    const int tid = threadIdx.x;
    const int lane = tid & 63, wv = tid >> 6;
    const int col = lane & 15, quad = lane >> 4;
    const int wm = wv >> 1, wn = wv & 1;
    const int n0 = blockIdx.x * 128, m0 = blockIdx.y * 128;

    f32x4 acc[4][4] = {};

    const bf16* Ag = Cx  + (size_t)m0 * K_;
    const bf16* Bg = W2T + (size_t)n0 * K_;

    for (int k0 = 0; k0 < K_; k0 += 32) {
        #pragma unroll
        for (int h = 0; h < 2; ++h) {
            int idx = tid + h * 256;
            int row = idx >> 2, c = (idx & 3) * 8;
            G2L16(Ag + (size_t)row * K_ + k0 + c, As + (size_t)idx * 8);
            G2L16(Bg + (size_t)row * K_ + k0 + c, Bs + (size_t)idx * 8);
        }
        __syncthreads();

        bf16x8 af[4], bfr[4];
        #pragma unroll
        for (int i = 0; i < 4; ++i)
            af[i] = *(const bf16x8*)&As[(wm * 64 + i * 16 + col) * 32 + quad * 8];
        #pragma unroll
        for (int j = 0; j < 4; ++j)
            bfr[j] = *(const bf16x8*)&Bs[(wn * 64 + j * 16 + col) * 32 + quad * 8];

        #pragma unroll
        for (int i = 0; i < 4; ++i)
            #pragma unroll
            for (int j = 0; j < 4; ++j)
                acc[i][j] = __builtin_amdgcn_mfma_f32_16x16x32_bf16(af[i], bfr[j], acc[i][j], 0, 0, 0);
        __syncthreads();
    }

    #pragma unroll
    for (int i = 0; i < 4; ++i) {
        #pragma unroll
        for (int r = 0; r < 4; ++r) {
            int m = m0 + wm * 64 + i * 16 + quad * 4 + r;
            #pragma unroll
            for (int j = 0; j < 4; ++j) {
                int n = n0 + wn * 64 + j * 16 + col;
                OUT[(size_t)m * H_ + n] = acc[i][j][r] + B2[n];
            }
        }
    }
}

// ---------------------------------------------------------------------------
extern "C" void kernel_launch(void* const* d_in, const int* in_sizes, int n_in,
                              void* d_out, int out_size, void* d_ws, size_t ws_size,
                              hipStream_t stream)
{
    const float* X  = (const float*)d_in[0];
    const float* W1 = (const float*)d_in[1];
    const float* B1 = (const float*)d_in[2];
    const float* W2 = (const float*)d_in[3];
    const float* B2 = (const float*)d_in[4];
    float* OUT = (float*)d_out;

    const size_t QE = (size_t)B_ * NH_ * S_ * DK_;   // 8,388,608
    bf16* Qw  = (bf16*)d_ws;
    bf16* Kw  = Qw + QE;
    bf16* Vw  = Kw + QE;        // transposed [bh][d][s]
    bf16* Rw  = Vw + QE;        // W1T during qkv, ctx afterwards
    bf16* W1T = Rw;
    bf16* Cw  = Rw;
    bf16* W2T = Qw;             // overlays Q (dead after attn)
    bf16* Xb  = Rw + QE;        // only if ws permits (5*QE elems total)

    const bool fast = ws_size >= 5 * QE * sizeof(bf16);

    conv_wT<<<dim3(N1_ / 64, K_ / 64), 256, 0, stream>>>(W1, W1T, K_, N1_);
    if (fast) {
        conv_x<<<dim3((int)(QE / (256 * 8))), 256, 0, stream>>>(X, Xb);
        gemm_qkv_mfma2<<<dim3(N1_ / 128, M_ / 128), 256, 0, stream>>>(Xb, W1T, B1, Qw, Kw, Vw);
    } else {
        gemm_qkv_mfma<<<dim3(N1_ / 128, M_ / 128), 256, 0, stream>>>(X, W1T, B1, Qw, Kw, Vw);
    }
    attn_mfma<<<dim3(S_ / 128, B_ * NH_), 512, 0, stream>>>(Qw, Kw, Vw, Cw);
    conv_wT<<<dim3(H_ / 64, K_ / 64), 256, 0, stream>>>(W2, W2T, K_, H_);
    gemm_out_mfma<<<dim3(H_ / 128, M_ / 128), 256, 0, stream>>>(Cw, W2T, B2, OUT);
}

// Round 8
// 310.713 us; speedup vs baseline: 1.0470x; 1.0470x over previous
//
#include <hip/hip_runtime.h>
#include <hip/hip_bf16.h>

// Problem: B=4, S=2048, H=1024, NH=16, DK=64. fp32 I/O.
// R16: R15 with the permlane32_swap (ISA semantics unverifiable here; prime
// suspect for R14/R15's ~1e-2 failures) replaced by __shfl_xor(,32) with
// HIP-defined semantics. pb routing derived from the HW-verified 32x32 C
// layout: dest lane (q,hi) word m of chunk c = w[2c+hi][m&1] from half
// hi'=(m>=2). Belief-cancellation safe (pb and va use the same believed
// slot->k map; precedent: R8-R13's LDS-routed P passed on this argument).
// l = ones*P on the matrix pipe with the SAME pb operand (consistent
// rounding). Keeps from R14/R15:
//  - 32x32x16 MFMAs: one b128 A-frag read feeds 32 q-rows (LDS-bound fix).
//  - Ks/Vs XOR swizzle (d ^= ((row>>3)&3)<<3, 72-pad).
//  - raw v_exp_f32 (R11), bijective XCD swizzle (R12, FETCH 139->25MB).
// GEMMs / converters unchanged.

typedef __hip_bfloat16 bf16;
typedef __attribute__((ext_vector_type(8))) short bf16x8;   // 8 bf16 = 4 VGPRs
typedef __attribute__((ext_vector_type(4))) float f32x4;
typedef __attribute__((ext_vector_type(16))) float f32x16;

#define B_   4
#define S_   2048
#define H_   1024
#define NH_  16
#define DK_  64
#define M_   8192   // B_*S_
#define N1_  3072
#define K_   1024

#define SCALE_Q 0.18033688f   // 0.125 * log2(e): softmax in exp2 domain

typedef const __attribute__((address_space(1))) void* gas_t;
typedef __attribute__((address_space(3))) void* las_t;
#define G2L16(g, l) __builtin_amdgcn_global_load_lds((gas_t)(g), (las_t)(l), 16, 0, 0)

#if __has_builtin(__builtin_amdgcn_exp2f)
#define EX2(x) __builtin_amdgcn_exp2f(x)
#else
#define EX2(x) exp2f(x)
#endif

__device__ __forceinline__ float b2f(bf16 v) { return __bfloat162float(v); }

// pack two fp32 -> two bf16 (RNE, finite inputs), 3 int ops + merge
__device__ __forceinline__ unsigned pk2(float a, float b) {
    unsigned ua = __float_as_uint(a);
    unsigned ub = __float_as_uint(b);
    ua += 0x7FFFu + ((ua >> 16) & 1u);
    ub += 0x7FFFu + ((ub >> 16) & 1u);
    return (ua >> 16) | (ub & 0xFFFF0000u);
}

// swizzled LDS elem offset for [64][72] bf16 tiles
__device__ __forceinline__ int swzi(int row, int d) {
    return row * 72 + (d ^ (((row >> 3) & 3) << 3));
}

// ---------------------------------------------------------------------------
// K-1: X fp32 -> bf16 (one-shot; removes cvt from the qkv K-loop)
// ---------------------------------------------------------------------------
__global__ __launch_bounds__(256) void conv_x(const float* __restrict__ X,
                                              bf16* __restrict__ Xb)
{
    size_t i = ((size_t)blockIdx.x * 256 + threadIdx.x) * 8;
    float4 lo = *(const float4*)&X[i];
    float4 hi = *(const float4*)&X[i + 4];
    uint4 u;
    u.x = pk2(lo.x, lo.y); u.y = pk2(lo.z, lo.w);
    u.z = pk2(hi.x, hi.y); u.w = pk2(hi.z, hi.w);
    *(uint4*)&Xb[i] = u;
}

// ---------------------------------------------------------------------------
// K0: convert + transpose weights: W [K][N] fp32 -> WT [N][K] bf16.
// ---------------------------------------------------------------------------
__global__ __launch_bounds__(256) void conv_wT(const float* __restrict__ W,
                                               bf16* __restrict__ WT,
                                               int Kdim, int Ndim)
{
    __shared__ bf16 T[64][72];
    const int tid = threadIdx.x;
    const int n0 = blockIdx.x * 64, k0 = blockIdx.y * 64;
    const int kr = tid >> 4, nc = (tid & 15) * 4;
    #pragma unroll
    for (int p = 0; p < 4; ++p) {
        float4 v = *(const float4*)&W[(size_t)(k0 + kr + p * 16) * Ndim + n0 + nc];
        T[nc + 0][kr + p * 16] = __float2bfloat16(v.x);
        T[nc + 1][kr + p * 16] = __float2bfloat16(v.y);
        T[nc + 2][kr + p * 16] = __float2bfloat16(v.z);
        T[nc + 3][kr + p * 16] = __float2bfloat16(v.w);
    }
    __syncthreads();
    const int nr = tid >> 2, kc = (tid & 3) * 16;
    *(bf16x8*)&WT[(size_t)(n0 + nr) * Kdim + k0 + kc]     = *(const bf16x8*)&T[nr][kc];
    *(bf16x8*)&WT[(size_t)(n0 + nr) * Kdim + k0 + kc + 8] = *(const bf16x8*)&T[nr][kc + 8];
}

// ---------------------------------------------------------------------------
// qkv epilogue shared by both variants
// ---------------------------------------------------------------------------
__device__ __forceinline__ void qkv_epilogue(
    const f32x4 acc[4][4], const float* __restrict__ B1,
    bf16* __restrict__ Qp, bf16* __restrict__ Kp, bf16* __restrict__ Vt,
    int n0, int m0, int wm, int wn, int quad, int col)
{
    const int which = n0 >> 10;          // 0=q 1=k 2=v
    const int bb = m0 >> 11;
    if (which == 2) {
        #pragma unroll
        for (int i = 0; i < 4; ++i) {
            int s = (m0 & (S_ - 1)) + wm * 64 + i * 16 + quad * 4;
            #pragma unroll
            for (int j = 0; j < 4; ++j) {
                int n = n0 + wn * 64 + j * 16 + col;
                int h = (n >> 6) & 15, d = n & 63;
                float bv = B1[n];
                uint2 t;
                t.x = pk2(acc[i][j][0] + bv, acc[i][j][1] + bv);
                t.y = pk2(acc[i][j][2] + bv, acc[i][j][3] + bv);
                *(uint2*)&Vt[(((size_t)(bb * NH_ + h)) * DK_ + d) * S_ + s] = t;
            }
        }
    } else {
        bf16* dst = which ? Kp : Qp;
        const float sc = which ? 1.0f : SCALE_Q;
        #pragma unroll
        for (int i = 0; i < 4; ++i) {
            #pragma unroll
            for (int r = 0; r < 4; ++r) {
                int s = (m0 & (S_ - 1)) + wm * 64 + i * 16 + quad * 4 + r;
                #pragma unroll
                for (int j = 0; j < 4; ++j) {
                    int n = n0 + wn * 64 + j * 16 + col;
                    int h = (n >> 6) & 15, d = n & 63;
                    dst[(((size_t)(bb * NH_ + h)) * S_ + s) * DK_ + d] =
                        __float2bfloat16((acc[i][j][r] + B1[n]) * sc);
                }
            }
        }
    }
}

// ---------------------------------------------------------------------------
// K1-fast: qkv = Xbf @ W1 + b1, pure m97 (G2L16 both operands).
// ---------------------------------------------------------------------------
__global__ __launch_bounds__(256) void gemm_qkv_mfma2(
    const bf16* __restrict__ Xb, const bf16* __restrict__ W1T,
    const float* __restrict__ B1,
    bf16* __restrict__ Qp, bf16* __restrict__ Kp, bf16* __restrict__ Vt)
{
    __shared__ bf16 As[128 * 32];
    __shared__ bf16 Bs[128 * 32];

    const int tid = threadIdx.x;
    const int lane = tid & 63, wv = tid >> 6;
    const int col = lane & 15, quad = lane >> 4;
    const int wm = wv >> 1, wn = wv & 1;
    const int n0 = blockIdx.x * 128, m0 = blockIdx.y * 128;

    f32x4 acc[4][4] = {};

    const bf16* Ag = Xb  + (size_t)m0 * K_;
    const bf16* Bg = W1T + (size_t)n0 * K_;

    for (int k0 = 0; k0 < K_; k0 += 32) {
        #pragma unroll
        for (int h = 0; h < 2; ++h) {
            int idx = tid + h * 256;
            int row = idx >> 2, c = (idx & 3) * 8;
            G2L16(Ag + (size_t)row * K_ + k0 + c, As + (size_t)idx * 8);
            G2L16(Bg + (size_t)row * K_ + k0 + c, Bs + (size_t)idx * 8);
        }
        __syncthreads();

        bf16x8 af[4], bfr[4];
        #pragma unroll
        for (int i = 0; i < 4; ++i)
            af[i] = *(const bf16x8*)&As[(wm * 64 + i * 16 + col) * 32 + quad * 8];
        #pragma unroll
        for (int j = 0; j < 4; ++j)
            bfr[j] = *(const bf16x8*)&Bs[(wn * 64 + j * 16 + col) * 32 + quad * 8];

        #pragma unroll
        for (int i = 0; i < 4; ++i)
            #pragma unroll
            for (int j = 0; j < 4; ++j)
                acc[i][j] = __builtin_amdgcn_mfma_f32_16x16x32_bf16(af[i], bfr[j], acc[i][j], 0, 0, 0);
        __syncthreads();
    }
    qkv_epilogue(acc, B1, Qp, Kp, Vt, n0, m0, wm, wn, quad, col);
}

// ---------------------------------------------------------------------------
// K1-fallback: qkv with in-loop fp32->bf16 A conversion.
// ---------------------------------------------------------------------------
__global__ __launch_bounds__(256) void gemm_qkv_mfma(
    const float* __restrict__ X, const bf16* __restrict__ W1T,
    const float* __restrict__ B1,
    bf16* __restrict__ Qp, bf16* __restrict__ Kp, bf16* __restrict__ Vt)
{
    __shared__ bf16 As[128 * 32];
    __shared__ bf16 Bs[128 * 32];

    const int tid = threadIdx.x;
    const int lane = tid & 63, wv = tid >> 6;
    const int col = lane & 15, quad = lane >> 4;
    const int wm = wv >> 1, wn = wv & 1;
    const int n0 = blockIdx.x * 128, m0 = blockIdx.y * 128;

    f32x4 acc[4][4] = {};

    const float* Ag = X   + (size_t)m0 * K_;
    const bf16*  Bg = W1T + (size_t)n0 * K_;

    for (int k0 = 0; k0 < K_; k0 += 32) {
        #pragma unroll
        for (int h = 0; h < 2; ++h) {
            int idx = tid + h * 256;
            int row = idx >> 2, c = (idx & 3) * 8;
            G2L16(Bg + (size_t)row * K_ + k0 + c, Bs + (size_t)idx * 8);
        }
        #pragma unroll
        for (int h = 0; h < 2; ++h) {
            int idx = tid + h * 256;
            int row = idx >> 2, c = (idx & 3) * 8;
            float4 lo = *(const float4*)&Ag[(size_t)row * K_ + k0 + c];
            float4 hi = *(const float4*)&Ag[(size_t)row * K_ + k0 + c + 4];
            uint4 u;
            u.x = pk2(lo.x, lo.y); u.y = pk2(lo.z, lo.w);
            u.z = pk2(hi.x, hi.y); u.w = pk2(hi.z, hi.w);
            *(uint4*)&As[(size_t)idx * 8] = u;
        }
        __syncthreads();

        bf16x8 af[4], bfr[4];
        #pragma unroll
        for (int i = 0; i < 4; ++i)
            af[i] = *(const bf16x8*)&As[(wm * 64 + i * 16 + col) * 32 + quad * 8];
        #pragma unroll
        for (int j = 0; j < 4; ++j)
            bfr[j] = *(const bf16x8*)&Bs[(wn * 64 + j * 16 + col) * 32 + quad * 8];

        #pragma unroll
        for (int i = 0; i < 4; ++i)
            #pragma unroll
            for (int j = 0; j < 4; ++j)
                acc[i][j] = __builtin_amdgcn_mfma_f32_16x16x32_bf16(af[i], bfr[j], acc[i][j], 0, 0, 0);
        __syncthreads();
    }
    qkv_epilogue(acc, B1, Qp, Kp, Vt, n0, m0, wm, wn, quad, col);
}

// ---------------------------------------------------------------------------
// K2: 32x32 transposed-dataflow MFMA flash attention, register-P softmax.
// Block = 256 threads (4 waves), 128 q-rows; wave owns 32 q-cols (col=lane&31).
//   S^T = K Q^T via 32x32x16. C (HW-verified): col=q, k=(r&3)+8(r>>2)+4hi.
//   P: exp2 -> pk2 pairs w[g][p] (k = 8g+4hi+2p+{0,1}) -> __shfl_xor(,32)
//   routes the cross-half words; pb word m of chunk c = w[2c+hi][m&1] from
//   half (m>=2). pb and Vs A-frags use the same believed slot map ->
//   layout-belief cancels (R8-R13 precedent).
//   O^T += Vt P^T; l = ones*P with the SAME pb (consistent rounding).
// LDS 18.4KB (Ks+Vs, XOR-swizzled).
// ---------------------------------------------------------------------------
__global__ __launch_bounds__(256, 4) void attn_mfma(
    const bf16* __restrict__ Q, const bf16* __restrict__ K,
    const bf16* __restrict__ Vt, bf16* __restrict__ CTX)
{
    __shared__ bf16 Ks[64 * 72];      // [k-row][d], swizzled
    __shared__ bf16 Vs[64 * 72];      // [d-row][k], swizzled

    const int tid  = threadIdx.x;
    const int wv   = tid >> 6;        // 0..3
    const int lane = tid & 63;
    const int c32  = lane & 31;
    const int hi   = lane >> 5;

    // bijective XCD swizzle (grid 1024 = 8 XCDs * 128)
    const int lid = blockIdx.x + (blockIdx.y << 4);    // gridDim.x == 16
    const int vid = (lid & 7) * 128 + (lid >> 3);
    const int bh = vid >> 4;
    const int q0 = (vid & 15) * 128;

    const bf16* Qg  = Q  + (size_t)bh * S_ * DK_;
    const bf16* Kg  = K  + (size_t)bh * S_ * DK_;
    const bf16* Vtg = Vt + (size_t)bh * DK_ * S_;

    const short oneb = (short)0x3F80;
    const bf16x8 ones8 = {oneb, oneb, oneb, oneb, oneb, oneb, oneb, oneb};

    // Q B-frags (believed map): lane(col=c32) holds Q[qrow][dc*16 + hi*8 + j]
    const int qrow = q0 + wv * 32 + c32;
    bf16x8 qf[4];
    #pragma unroll
    for (int dc = 0; dc < 4; ++dc)
        qf[dc] = *(const bf16x8*)&Qg[(size_t)qrow * DK_ + dc * 16 + hi * 8];

    f32x16 o0 = {};     // O^T d-tile 0 (d = 0..31)
    f32x16 o1 = {};     // O^T d-tile 1 (d = 32..63)
    f32x16 l_acc = {};  // ones*P: every reg holds l[q=c32] partial

    const int sr = tid >> 2;          // staging row 0..63
    const int e0 = (tid & 3) * 16;    // 16 bf16 (2 x b128) per thread per buf

    // prefetch tile 0
    bf16x8 kreg0 = *(const bf16x8*)&Kg[(size_t)sr * DK_ + e0];
    bf16x8 kreg1 = *(const bf16x8*)&Kg[(size_t)sr * DK_ + e0 + 8];
    bf16x8 vreg0 = *(const bf16x8*)&Vtg[(size_t)sr * S_ + e0];
    bf16x8 vreg1 = *(const bf16x8*)&Vtg[(size_t)sr * S_ + e0 + 8];

    for (int kt = 0; kt < S_ / 64; ++kt) {
        *(bf16x8*)&Ks[swzi(sr, e0)]     = kreg0;
        *(bf16x8*)&Ks[swzi(sr, e0 + 8)] = kreg1;
        *(bf16x8*)&Vs[swzi(sr, e0)]     = vreg0;
        *(bf16x8*)&Vs[swzi(sr, e0 + 8)] = vreg1;
        __syncthreads();

        if (kt + 1 < S_ / 64) {
            kreg0 = *(const bf16x8*)&Kg[(size_t)((kt + 1) * 64 + sr) * DK_ + e0];
            kreg1 = *(const bf16x8*)&Kg[(size_t)((kt + 1) * 64 + sr) * DK_ + e0 + 8];
            vreg0 = *(const bf16x8*)&Vtg[(size_t)sr * S_ + (kt + 1) * 64 + e0];
            vreg1 = *(const bf16x8*)&Vtg[(size_t)sr * S_ + (kt + 1) * 64 + e0 + 8];
        }

        #pragma unroll
        for (int ks = 0; ks < 2; ++ks) {    // two 32-k subtiles per kt
            // S^T = K Q^T over d=64 (4 x K=16 MFMAs)
            f32x16 acc = {};
            #pragma unroll
            for (int dc = 0; dc < 4; ++dc) {
                bf16x8 ka = *(const bf16x8*)&Ks[swzi(ks * 32 + c32, dc * 16 + hi * 8)];
                acc = __builtin_amdgcn_mfma_f32_32x32x16_bf16(ka, qf[dc], acc, 0, 0, 0);
            }
            // exp2
            float e[16];
            #pragma unroll
            for (int r = 0; r < 16; ++r) e[r] = EX2(acc[r]);
            // pack: w[g][p] holds bf16 pair k = 8g + 4hi + 2p + {0,1}
            unsigned w[4][2];
            #pragma unroll
            for (int g = 0; g < 4; ++g) {
                w[g][0] = pk2(e[4 * g + 0], e[4 * g + 1]);
                w[g][1] = pk2(e[4 * g + 2], e[4 * g + 3]);
            }
            // per 16-k chunk c: shfl_xor-route cross-half words, assemble pb
            #pragma unroll
            for (int c = 0; c < 2; ++c) {
                unsigned z0 = hi ? w[2 * c][0] : w[2 * c + 1][0];
                unsigned z1 = hi ? w[2 * c][1] : w[2 * c + 1][1];
                unsigned x0 = (unsigned)__shfl_xor((int)z0, 32, 64);
                unsigned x1 = (unsigned)__shfl_xor((int)z1, 32, 64);
                union { unsigned u[4]; bf16x8 v; } pb;
                pb.u[0] = hi ? x0 : w[2 * c][0];
                pb.u[1] = hi ? x1 : w[2 * c][1];
                pb.u[2] = hi ? w[2 * c + 1][0] : x0;
                pb.u[3] = hi ? w[2 * c + 1][1] : x1;
                const int gk = ks * 2 + c;
                bf16x8 va0 = *(const bf16x8*)&Vs[swzi(c32,      gk * 16 + hi * 8)];
                bf16x8 va1 = *(const bf16x8*)&Vs[swzi(32 + c32, gk * 16 + hi * 8)];
                l_acc = __builtin_amdgcn_mfma_f32_32x32x16_bf16(ones8, pb.v, l_acc, 0, 0, 0);
                o0 = __builtin_amdgcn_mfma_f32_32x32x16_bf16(va0, pb.v, o0, 0, 0, 0);
                o1 = __builtin_amdgcn_mfma_f32_32x32x16_bf16(va1, pb.v, o1, 0, 0, 0);
            }
        }
        __syncthreads();
    }

    // l[q=c32] is in every reg of l_acc (A=ones): use reg 0
    const float inv = 1.f / l_acc[0];

    // epilogue: lane holds O^T[d][q=c32], d = dt*32 + 8g + 4hi + m
    const int b = bh >> 4, h = bh & 15;
    bf16* crow = CTX + ((size_t)(b * S_ + qrow)) * H_ + h * DK_;
    #pragma unroll
    for (int g = 0; g < 4; ++g) {
        uint2 t0, t1;
        t0.x = pk2(o0[4 * g + 0] * inv, o0[4 * g + 1] * inv);
        t0.y = pk2(o0[4 * g + 2] * inv, o0[4 * g + 3] * inv);
        *(uint2*)&crow[g * 8 + hi * 4] = t0;
        t1.x = pk2(o1[4 * g + 0] * inv, o1[4 * g + 1] * inv);
        t1.y = pk2(o1[4 * g + 2] * inv, o1[4 * g + 3] * inv);
        *(uint2*)&crow[32 + g * 8 + hi * 4] = t1;
    }
}

// ---------------------------------------------------------------------------
// K3: out = ctx @ W2 + b2 (MFMA).
// ---------------------------------------------------------------------------
__global__ __launch_bounds__(256) void gemm_out_mfma(
    const bf16* __restrict__ Cx, const bf16* __restrict__ W2T,
    const float* __restrict__ B2, float* __restrict__ OUT)
{
    __shared__ bf16 As[128 * 32];
    __shared__ bf16 Bs[128 * 32];

    const int tid = threadIdx.x;
    const int lane = tid & 63, wv = tid >> 6;
    const int col = lane & 15, quad = lane >> 4;
    const int wm = wv >> 1, wn = wv & 1;
    const int n0 = blockIdx.x * 128, m0 = blockIdx.y * 128;

    f32x4 acc[4][4] = {};

    const bf16* Ag = Cx  + (size_t)m0 * K_;
    const bf16* Bg = W2T + (size_t)n0 * K_;

    for (int k0 = 0; k0 < K_; k0 += 32) {
        #pragma unroll
        for (int h = 0; h < 2; ++h) {
            int idx = tid + h * 256;
            int row = idx >> 2, c = (idx & 3) * 8;
            G2L16(Ag + (size_t)row * K_ + k0 + c, As + (size_t)idx * 8);
            G2L16(Bg + (size_t)row * K_ + k0 + c, Bs + (size_t)idx * 8);
        }
        __syncthreads();

        bf16x8 af[4], bfr[4];
        #pragma unroll
        for (int i = 0; i < 4; ++i)
            af[i] = *(const bf16x8*)&As[(wm * 64 + i * 16 + col) * 32 + quad * 8];
        #pragma unroll
        for (int j = 0; j < 4; ++j)
            bfr[j] = *(const bf16x8*)&Bs[(wn * 64 + j * 16 + col) * 32 + quad * 8];

        #pragma unroll
        for (int i = 0; i < 4; ++i)
            #pragma unroll
            for (int j = 0; j < 4; ++j)
                acc[i][j] = __builtin_amdgcn_mfma_f32_16x16x32_bf16(af[i], bfr[j], acc[i][j], 0, 0, 0);
        __syncthreads();
    }

    #pragma unroll
    for (int i = 0; i < 4; ++i) {
        #pragma unroll
        for (int r = 0; r < 4; ++r) {
            int m = m0 + wm * 64 + i * 16 + quad * 4 + r;
            #pragma unroll
            for (int j = 0; j < 4; ++j) {
                int n = n0 + wn * 64 + j * 16 + col;
                OUT[(size_t)m * H_ + n] = acc[i][j][r] + B2[n];
            }
        }
    }
}

// ---------------------------------------------------------------------------
extern "C" void kernel_launch(void* const* d_in, const int* in_sizes, int n_in,
                              void* d_out, int out_size, void* d_ws, size_t ws_size,
                              hipStream_t stream)
{
    const float* X  = (const float*)d_in[0];
    const float* W1 = (const float*)d_in[1];
    const float* B1 = (const float*)d_in[2];
    const float* W2 = (const float*)d_in[3];
    const float* B2 = (const float*)d_in[4];
    float* OUT = (float*)d_out;

    const size_t QE = (size_t)B_ * NH_ * S_ * DK_;   // 8,388,608
    bf16* Qw  = (bf16*)d_ws;
    bf16* Kw  = Qw + QE;
    bf16* Vw  = Kw + QE;        // transposed [bh][d][s]
    bf16* Rw  = Vw + QE;        // W1T during qkv, ctx afterwards
    bf16* W1T = Rw;
    bf16* Cw  = Rw;
    bf16* W2T = Qw;             // overlays Q (dead after attn)
    bf16* Xb  = Rw + QE;        // only if ws permits (5*QE elems total)

    const bool fast = ws_size >= 5 * QE * sizeof(bf16);

    conv_wT<<<dim3(N1_ / 64, K_ / 64), 256, 0, stream>>>(W1, W1T, K_, N1_);
    if (fast) {
        conv_x<<<dim3((int)(QE / (256 * 8))), 256, 0, stream>>>(X, Xb);
        gemm_qkv_mfma2<<<dim3(N1_ / 128, M_ / 128), 256, 0, stream>>>(Xb, W1T, B1, Qw, Kw, Vw);
    } else {
        gemm_qkv_mfma<<<dim3(N1_ / 128, M_ / 128), 256, 0, stream>>>(X, W1T, B1, Qw, Kw, Vw);
    }
    attn_mfma<<<dim3(S_ / 128, B_ * NH_), 256, 0, stream>>>(Qw, Kw, Vw, Cw);
    conv_wT<<<dim3(H_ / 64, K_ / 64), 256, 0, stream>>>(W2, W2T, K_, H_);
    gemm_out_mfma<<<dim3(H_ / 128, M_ / 128), 256, 0, stream>>>(Cw, W2T, B2, OUT);
}

// Round 9
// 286.487 us; speedup vs baseline: 1.1356x; 1.0846x over previous
//
#include <hip/hip_runtime.h>
#include <hip/hip_bf16.h>

// Problem: B=4, S=2048, H=1024, NH=16, DK=64. fp32 I/O.
// R17: consolidation. 32x32 attn arc (R14-R16) abandoned: R16 passed but
// ran 114us (shfl_xor lowers to ds_bpermute = LDS pipe; XOR swizzle left
// conflicts at 1.68e7 since row*36 mod 32 ignores row>>3). Revert attn to
// R11's verified 102us kernel (256-thr, 2-q-subtile, Ps-LDS, all-K=32)
// + bijective XCD swizzle (R12-proven: FETCH 139->25MB, index-only).
// NEW: same XCD swizzle on both MFMA GEMMs (qkv 1536 blk = 8x192, out
// 512 = 8x64): each XCD owns a contiguous m-slab -> A-slab L2-resident.
// Index remaps only; numerics bit-identical to R11.

typedef __hip_bfloat16 bf16;
typedef __attribute__((ext_vector_type(8))) short bf16x8;  // 8 bf16 = 4 VGPRs
typedef __attribute__((ext_vector_type(4))) float f32x4;

#define B_   4
#define S_   2048
#define H_   1024
#define NH_  16
#define DK_  64
#define M_   8192   // B_*S_
#define N1_  3072
#define K_   1024

#define SCALE_Q 0.18033688f   // 0.125 * log2(e): softmax in exp2 domain

typedef const __attribute__((address_space(1))) void* gas_t;
typedef __attribute__((address_space(3))) void* las_t;
#define G2L16(g, l) __builtin_amdgcn_global_load_lds((gas_t)(g), (las_t)(l), 16, 0, 0)

#if __has_builtin(__builtin_amdgcn_exp2f)
#define EX2(x) __builtin_amdgcn_exp2f(x)
#else
#define EX2(x) exp2f(x)
#endif

__device__ __forceinline__ float b2f(bf16 v) { return __bfloat162float(v); }

// pack two fp32 -> two bf16 (RNE, finite inputs), 3 int ops + merge
__device__ __forceinline__ unsigned pk2(float a, float b) {
    unsigned ua = __float_as_uint(a);
    unsigned ub = __float_as_uint(b);
    ua += 0x7FFFu + ((ua >> 16) & 1u);
    ub += 0x7FFFu + ((ub >> 16) & 1u);
    return (ua >> 16) | (ub & 0xFFFF0000u);
}

// bijective XCD swizzle for linear block id (nwg % 8 == 0):
// dispatch round-robins lid%8 across XCDs; give XCD x the contiguous
// virtual range [x*nwg/8, (x+1)*nwg/8).
__device__ __forceinline__ int xcd_swz(int lid, int nwg) {
    return (lid & 7) * (nwg >> 3) + (lid >> 3);
}

// ---------------------------------------------------------------------------
// K-1: X fp32 -> bf16 (one-shot; removes cvt from the qkv K-loop)
// ---------------------------------------------------------------------------
__global__ __launch_bounds__(256) void conv_x(const float* __restrict__ X,
                                              bf16* __restrict__ Xb)
{
    size_t i = ((size_t)blockIdx.x * 256 + threadIdx.x) * 8;
    float4 lo = *(const float4*)&X[i];
    float4 hi = *(const float4*)&X[i + 4];
    uint4 u;
    u.x = pk2(lo.x, lo.y); u.y = pk2(lo.z, lo.w);
    u.z = pk2(hi.x, hi.y); u.w = pk2(hi.z, hi.w);
    *(uint4*)&Xb[i] = u;
}

// ---------------------------------------------------------------------------
// K0: convert + transpose weights: W [K][N] fp32 -> WT [N][K] bf16.
// ---------------------------------------------------------------------------
__global__ __launch_bounds__(256) void conv_wT(const float* __restrict__ W,
                                               bf16* __restrict__ WT,
                                               int Kdim, int Ndim)
{
    __shared__ bf16 T[64][72];
    const int tid = threadIdx.x;
    const int n0 = blockIdx.x * 64, k0 = blockIdx.y * 64;
    const int kr = tid >> 4, nc = (tid & 15) * 4;
    #pragma unroll
    for (int p = 0; p < 4; ++p) {
        float4 v = *(const float4*)&W[(size_t)(k0 + kr + p * 16) * Ndim + n0 + nc];
        T[nc + 0][kr + p * 16] = __float2bfloat16(v.x);
        T[nc + 1][kr + p * 16] = __float2bfloat16(v.y);
        T[nc + 2][kr + p * 16] = __float2bfloat16(v.z);
        T[nc + 3][kr + p * 16] = __float2bfloat16(v.w);
    }
    __syncthreads();
    const int nr = tid >> 2, kc = (tid & 3) * 16;
    *(bf16x8*)&WT[(size_t)(n0 + nr) * Kdim + k0 + kc]     = *(const bf16x8*)&T[nr][kc];
    *(bf16x8*)&WT[(size_t)(n0 + nr) * Kdim + k0 + kc + 8] = *(const bf16x8*)&T[nr][kc + 8];
}

// ---------------------------------------------------------------------------
// qkv epilogue shared by both variants
// ---------------------------------------------------------------------------
__device__ __forceinline__ void qkv_epilogue(
    const f32x4 acc[4][4], const float* __restrict__ B1,
    bf16* __restrict__ Qp, bf16* __restrict__ Kp, bf16* __restrict__ Vt,
    int n0, int m0, int wm, int wn, int quad, int col)
{
    const int which = n0 >> 10;          // 0=q 1=k 2=v
    const int bb = m0 >> 11;
    if (which == 2) {
        #pragma unroll
        for (int i = 0; i < 4; ++i) {
            int s = (m0 & (S_ - 1)) + wm * 64 + i * 16 + quad * 4;
            #pragma unroll
            for (int j = 0; j < 4; ++j) {
                int n = n0 + wn * 64 + j * 16 + col;
                int h = (n >> 6) & 15, d = n & 63;
                float bv = B1[n];
                uint2 t;
                t.x = pk2(acc[i][j][0] + bv, acc[i][j][1] + bv);
                t.y = pk2(acc[i][j][2] + bv, acc[i][j][3] + bv);
                *(uint2*)&Vt[(((size_t)(bb * NH_ + h)) * DK_ + d) * S_ + s] = t;
            }
        }
    } else {
        bf16* dst = which ? Kp : Qp;
        const float sc = which ? 1.0f : SCALE_Q;
        #pragma unroll
        for (int i = 0; i < 4; ++i) {
            #pragma unroll
            for (int r = 0; r < 4; ++r) {
                int s = (m0 & (S_ - 1)) + wm * 64 + i * 16 + quad * 4 + r;
                #pragma unroll
                for (int j = 0; j < 4; ++j) {
                    int n = n0 + wn * 64 + j * 16 + col;
                    int h = (n >> 6) & 15, d = n & 63;
                    dst[(((size_t)(bb * NH_ + h)) * S_ + s) * DK_ + d] =
                        __float2bfloat16((acc[i][j][r] + B1[n]) * sc);
                }
            }
        }
    }
}

// ---------------------------------------------------------------------------
// K1-fast: qkv = Xbf @ W1 + b1, pure m97 (G2L16 both operands), XCD-swizzled.
// ---------------------------------------------------------------------------
__global__ __launch_bounds__(256) void gemm_qkv_mfma2(
    const bf16* __restrict__ Xb, const bf16* __restrict__ W1T,
    const float* __restrict__ B1,
    bf16* __restrict__ Qp, bf16* __restrict__ Kp, bf16* __restrict__ Vt)
{
    __shared__ bf16 As[128 * 32];
    __shared__ bf16 Bs[128 * 32];

    const int tid = threadIdx.x;
    const int lane = tid & 63, wv = tid >> 6;
    const int col = lane & 15, quad = lane >> 4;
    const int wm = wv >> 1, wn = wv & 1;
    const int lid = blockIdx.x + blockIdx.y * gridDim.x;
    const int vid = xcd_swz(lid, gridDim.x * gridDim.y);
    const int n0 = (vid % gridDim.x) * 128, m0 = (vid / gridDim.x) * 128;

    f32x4 acc[4][4] = {};

    const bf16* Ag = Xb  + (size_t)m0 * K_;
    const bf16* Bg = W1T + (size_t)n0 * K_;

    for (int k0 = 0; k0 < K_; k0 += 32) {
        #pragma unroll
        for (int h = 0; h < 2; ++h) {
            int idx = tid + h * 256;
            int row = idx >> 2, c = (idx & 3) * 8;
            G2L16(Ag + (size_t)row * K_ + k0 + c, As + (size_t)idx * 8);
            G2L16(Bg + (size_t)row * K_ + k0 + c, Bs + (size_t)idx * 8);
        }
        __syncthreads();

        bf16x8 af[4], bfr[4];
        #pragma unroll
        for (int i = 0; i < 4; ++i)
            af[i] = *(const bf16x8*)&As[(wm * 64 + i * 16 + col) * 32 + quad * 8];
        #pragma unroll
        for (int j = 0; j < 4; ++j)
            bfr[j] = *(const bf16x8*)&Bs[(wn * 64 + j * 16 + col) * 32 + quad * 8];

        #pragma unroll
        for (int i = 0; i < 4; ++i)
            #pragma unroll
            for (int j = 0; j < 4; ++j)
                acc[i][j] = __builtin_amdgcn_mfma_f32_16x16x32_bf16(af[i], bfr[j], acc[i][j], 0, 0, 0);
        __syncthreads();
    }
    qkv_epilogue(acc, B1, Qp, Kp, Vt, n0, m0, wm, wn, quad, col);
}

// ---------------------------------------------------------------------------
// K1-fallback: qkv with in-loop fp32->bf16 A conversion, XCD-swizzled.
// ---------------------------------------------------------------------------
__global__ __launch_bounds__(256) void gemm_qkv_mfma(
    const float* __restrict__ X, const bf16* __restrict__ W1T,
    const float* __restrict__ B1,
    bf16* __restrict__ Qp, bf16* __restrict__ Kp, bf16* __restrict__ Vt)
{
    __shared__ bf16 As[128 * 32];
    __shared__ bf16 Bs[128 * 32];

    const int tid = threadIdx.x;
    const int lane = tid & 63, wv = tid >> 6;
    const int col = lane & 15, quad = lane >> 4;
    const int wm = wv >> 1, wn = wv & 1;
    const int lid = blockIdx.x + blockIdx.y * gridDim.x;
    const int vid = xcd_swz(lid, gridDim.x * gridDim.y);
    const int n0 = (vid % gridDim.x) * 128, m0 = (vid / gridDim.x) * 128;

    f32x4 acc[4][4] = {};

    const float* Ag = X   + (size_t)m0 * K_;
    const bf16*  Bg = W1T + (size_t)n0 * K_;

    for (int k0 = 0; k0 < K_; k0 += 32) {
        #pragma unroll
        for (int h = 0; h < 2; ++h) {
            int idx = tid + h * 256;
            int row = idx >> 2, c = (idx & 3) * 8;
            G2L16(Bg + (size_t)row * K_ + k0 + c, Bs + (size_t)idx * 8);
        }
        #pragma unroll
        for (int h = 0; h < 2; ++h) {
            int idx = tid + h * 256;
            int row = idx >> 2, c = (idx & 3) * 8;
            float4 lo = *(const float4*)&Ag[(size_t)row * K_ + k0 + c];
            float4 hi = *(const float4*)&Ag[(size_t)row * K_ + k0 + c + 4];
            uint4 u;
            u.x = pk2(lo.x, lo.y); u.y = pk2(lo.z, lo.w);
            u.z = pk2(hi.x, hi.y); u.w = pk2(hi.z, hi.w);
            *(uint4*)&As[(size_t)idx * 8] = u;
        }
        __syncthreads();

        bf16x8 af[4], bfr[4];
        #pragma unroll
        for (int i = 0; i < 4; ++i)
            af[i] = *(const bf16x8*)&As[(wm * 64 + i * 16 + col) * 32 + quad * 8];
        #pragma unroll
        for (int j = 0; j < 4; ++j)
            bfr[j] = *(const bf16x8*)&Bs[(wn * 64 + j * 16 + col) * 32 + quad * 8];

        #pragma unroll
        for (int i = 0; i < 4; ++i)
            #pragma unroll
            for (int j = 0; j < 4; ++j)
                acc[i][j] = __builtin_amdgcn_mfma_f32_16x16x32_bf16(af[i], bfr[j], acc[i][j], 0, 0, 0);
        __syncthreads();
    }
    qkv_epilogue(acc, B1, Qp, Kp, Vt, n0, m0, wm, wn, quad, col);
}

// ---------------------------------------------------------------------------
// K2: transposed-dataflow MFMA flash attention, 2 q-subtiles per wave.
// (R11's verified kernel + XCD swizzle.)
// Block = 256 threads (4 waves), 128 q-rows; wave owns 32 rows (2 x 16).
//   S^T = K*Q^T  (A = Ks rows — loaded ONCE, used for both q-sets)
//   P = exp2(S^T) (raw v_exp_f32 + manual-RNE pk2)
//   O^T = Vt*P^T (A = Vs rows — loaded once, used for both q-sets)
//   l = ones*P^T on the MFMA pipe, col-indexed for the epilogue.
// ---------------------------------------------------------------------------
__global__ __launch_bounds__(256, 4) void attn_mfma(
    const bf16* __restrict__ Q, const bf16* __restrict__ K,
    const bf16* __restrict__ Vt, bf16* __restrict__ CTX)
{
    __shared__ bf16 Ks[64][72];         // [c][d]
    __shared__ bf16 Vs[64][72];         // [d][c]
    __shared__ bf16 Ps[4][2][16][72];   // per-wave, per-q-set P [r][c]

    const int tid  = threadIdx.x;
    const int wv   = tid >> 6;       // 0..3
    const int lane = tid & 63;
    const int col  = lane & 15;
    const int quad = lane >> 4;

    // bijective XCD swizzle: all 16 q-tiles of a bh land on one XCD
    const int lid = blockIdx.x + (blockIdx.y << 4);    // gridDim.x == 16
    const int vid = (lid & 7) * 128 + (lid >> 3);
    const int bh = vid >> 4;
    const int q0 = (vid & 15) * 128;

    const bf16* Qg  = Q  + (size_t)bh * S_ * DK_;
    const bf16* Kg  = K  + (size_t)bh * S_ * DK_;
    const bf16* Vtg = Vt + (size_t)bh * DK_ * S_;

    const short oneb = (short)0x3F80;
    const bf16x8 ones = {oneb, oneb, oneb, oneb, oneb, oneb, oneb, oneb};

    // Q fragments (B operand): lane(col) holds q-row q0 + wv*32 + qs*16 + col
    bf16x8 qf[2][2];
    #pragma unroll
    for (int qs = 0; qs < 2; ++qs) {
        const int qrow = q0 + wv * 32 + qs * 16 + col;
        qf[qs][0] = *(const bf16x8*)&Qg[(size_t)qrow * DK_ + quad * 8];
        qf[qs][1] = *(const bf16x8*)&Qg[(size_t)qrow * DK_ + 32 + quad * 8];
    }

    f32x4 o[2][4] = {};                 // O^T, d-subtiles per q-set
    f32x4 l_acc[2] = {};                // row sums, col-indexed

    const int sr = tid >> 2;            // staging row 0..63 (256 threads)
    const int e0 = (tid & 3) * 16;      // 16 bf16 (2 x b128) per thread per buf

    // prefetch tile 0
    bf16x8 kreg0 = *(const bf16x8*)&Kg[(size_t)sr * DK_ + e0];
    bf16x8 kreg1 = *(const bf16x8*)&Kg[(size_t)sr * DK_ + e0 + 8];
    bf16x8 vreg0 = *(const bf16x8*)&Vtg[(size_t)sr * S_ + e0];
    bf16x8 vreg1 = *(const bf16x8*)&Vtg[(size_t)sr * S_ + e0 + 8];

    for (int kt = 0; kt < S_ / 64; ++kt) {
        *(bf16x8*)&Ks[sr][e0]     = kreg0;
        *(bf16x8*)&Ks[sr][e0 + 8] = kreg1;
        *(bf16x8*)&Vs[sr][e0]     = vreg0;
        *(bf16x8*)&Vs[sr][e0 + 8] = vreg1;
        __syncthreads();

        if (kt + 1 < S_ / 64) {
            kreg0 = *(const bf16x8*)&Kg[(size_t)((kt + 1) * 64 + sr) * DK_ + e0];
            kreg1 = *(const bf16x8*)&Kg[(size_t)((kt + 1) * 64 + sr) * DK_ + e0 + 8];
            vreg0 = *(const bf16x8*)&Vtg[(size_t)sr * S_ + (kt + 1) * 64 + e0];
            vreg1 = *(const bf16x8*)&Vtg[(size_t)sr * S_ + (kt + 1) * 64 + e0 + 8];
        }

        // S^T = K Q^T: K-fragments loaded once, two MFMAs (one per q-set).
        #pragma unroll
        for (int cs = 0; cs < 4; ++cs) {
            const bf16* kb = &Ks[cs * 16 + col][0];
            bf16x8 ka0 = *(const bf16x8*)&kb[quad * 8];
            bf16x8 ka1 = *(const bf16x8*)&kb[32 + quad * 8];
            #pragma unroll
            for (int qs = 0; qs < 2; ++qs) {
                f32x4 a = {0.f, 0.f, 0.f, 0.f};
                a = __builtin_amdgcn_mfma_f32_16x16x32_bf16(ka0, qf[qs][0], a, 0, 0, 0);
                a = __builtin_amdgcn_mfma_f32_16x16x32_bf16(ka1, qf[qs][1], a, 0, 0, 0);
                uint2 p;
                p.x = pk2(EX2(a[0]), EX2(a[1]));
                p.y = pk2(EX2(a[2]), EX2(a[3]));
                *(uint2*)&Ps[wv][qs][col][cs * 16 + quad * 4] = p;
            }
        }

        // read P as B-frags (same wave wrote it; per-wave buffer, no barrier)
        bf16x8 pf[2][2];
        #pragma unroll
        for (int qs = 0; qs < 2; ++qs) {
            pf[qs][0] = *(const bf16x8*)&Ps[wv][qs][col][quad * 8];
            pf[qs][1] = *(const bf16x8*)&Ps[wv][qs][col][32 + quad * 8];
            // l += 1^T P (matrix pipe; every reg holds l[col])
            l_acc[qs] = __builtin_amdgcn_mfma_f32_16x16x32_bf16(ones, pf[qs][0], l_acc[qs], 0, 0, 0);
            l_acc[qs] = __builtin_amdgcn_mfma_f32_16x16x32_bf16(ones, pf[qs][1], l_acc[qs], 0, 0, 0);
        }

        // O^T += Vt P^T: V-fragments loaded once, two MFMAs each.
        #pragma unroll
        for (int ds = 0; ds < 4; ++ds) {
            const bf16* vb = &Vs[ds * 16 + col][0];
            bf16x8 va0 = *(const bf16x8*)&vb[quad * 8];
            bf16x8 va1 = *(const bf16x8*)&vb[32 + quad * 8];
            #pragma unroll
            for (int qs = 0; qs < 2; ++qs) {
                o[qs][ds] = __builtin_amdgcn_mfma_f32_16x16x32_bf16(va0, pf[qs][0], o[qs][ds], 0, 0, 0);
                o[qs][ds] = __builtin_amdgcn_mfma_f32_16x16x32_bf16(va1, pf[qs][1], o[qs][ds], 0, 0, 0);
            }
        }
        __syncthreads();
    }

    // epilogue: O^T C-layout -> 4 contiguous d per lane -> packed 8B stores
    const int b = bh >> 4, h = bh & 15;
    #pragma unroll
    for (int qs = 0; qs < 2; ++qs) {
        const float inv = 1.f / l_acc[qs][0];
        const int srow = q0 + wv * 32 + qs * 16 + col;
        bf16* crow = CTX + ((size_t)(b * S_ + srow)) * H_ + h * DK_;
        #pragma unroll
        for (int ds = 0; ds < 4; ++ds) {
            uint2 t;
            t.x = pk2(o[qs][ds][0] * inv, o[qs][ds][1] * inv);
            t.y = pk2(o[qs][ds][2] * inv, o[qs][ds][3] * inv);
            *(uint2*)&crow[ds * 16 + quad * 4] = t;
        }
    }
}

// ---------------------------------------------------------------------------
// K3: out = ctx @ W2 + b2 (MFMA), XCD-swizzled.
// ---------------------------------------------------------------------------
__global__ __launch_bounds__(256) void gemm_out_mfma(
    const bf16* __restrict__ Cx, const bf16* __restrict__ W2T,
    const float* __restrict__ B2, float* __restrict__ OUT)
{
    __shared__ bf16 As[128 * 32];
    __shared__ bf16 Bs[128 * 32];

    const int tid = threadIdx.x;
    const int lane = tid & 63, wv = tid >> 6;
    const int col = lane & 15, quad = lane >> 4;
    const int wm = wv >> 1, wn = wv & 1;
    const int lid = blockIdx.x + blockIdx.y * gridDim.x;
    const int vid = xcd_swz(lid, gridDim.x * gridDim.y);
    const int n0 = (vid % gridDim.x) * 128, m0 = (vid / gridDim.x) * 128;

    f32x4 acc[4][4] = {};

    const bf16* Ag = Cx  + (size_t)m0 * K_;
    const bf16* Bg = W2T + (size_t)n0 * K_;

    for (int k0 = 0; k0 < K_; k0 += 32) {
        #pragma unroll
        for (int h = 0; h < 2; ++h) {
            int idx = tid + h * 256;
            int row = idx >> 2, c = (idx & 3) * 8;
            G2L16(Ag + (size_t)row * K_ + k0 + c, As + (size_t)idx * 8);
            G2L16(Bg + (size_t)row * K_ + k0 + c, Bs + (size_t)idx * 8);
        }
        __syncthreads();

        bf16x8 af[4], bfr[4];
        #pragma unroll
        for (int i = 0; i < 4; ++i)
            af[i] = *(const bf16x8*)&As[(wm * 64 + i * 16 + col) * 32 + quad * 8];
        #pragma unroll
        for (int j = 0; j < 4; ++j)
            bfr[j] = *(const bf16x8*)&Bs[(wn * 64 + j * 16 + col) * 32 + quad * 8];

        #pragma unroll
        for (int i = 0; i < 4; ++i)
            #pragma unroll
            for (int j = 0; j < 4; ++j)
                acc[i][j] = __builtin_amdgcn_mfma_f32_16x16x32_bf16(af[i], bfr[j], acc[i][j], 0, 0, 0);
        __syncthreads();
    }

    #pragma unroll
    for (int i = 0; i < 4; ++i) {
        #pragma unroll
        for (int r = 0; r < 4; ++r) {
            int m = m0 + wm * 64 + i * 16 + quad * 4 + r;
            #pragma unroll
            for (int j = 0; j < 4; ++j) {
                int n = n0 + wn * 64 + j * 16 + col;
                OUT[(size_t)m * H_ + n] = acc[i][j][r] + B2[n];
            }
        }
    }
}

// ---------------------------------------------------------------------------
extern "C" void kernel_launch(void* const* d_in, const int* in_sizes, int n_in,
                              void* d_out, int out_size, void* d_ws, size_t ws_size,
                              hipStream_t stream)
{
    const float* X  = (const float*)d_in[0];
    const float* W1 = (const float*)d_in[1];
    const float* B1 = (const float*)d_in[2];
    const float* W2 = (const float*)d_in[3];
    const float* B2 = (const float*)d_in[4];
    float* OUT = (float*)d_out;

    const size_t QE = (size_t)B_ * NH_ * S_ * DK_;   // 8,388,608
    bf16* Qw  = (bf16*)d_ws;
    bf16* Kw  = Qw + QE;
    bf16* Vw  = Kw + QE;        // transposed [bh][d][s]
    bf16* Rw  = Vw + QE;        // W1T during qkv, ctx afterwards
    bf16* W1T = Rw;
    bf16* Cw  = Rw;
    bf16* W2T = Qw;             // overlays Q (dead after attn)
    bf16* Xb  = Rw + QE;        // only if ws permits (5*QE elems total)

    const bool fast = ws_size >= 5 * QE * sizeof(bf16);

    conv_wT<<<dim3(N1_ / 64, K_ / 64), 256, 0, stream>>>(W1, W1T, K_, N1_);
    if (fast) {
        conv_x<<<dim3((int)(QE / (256 * 8))), 256, 0, stream>>>(X, Xb);
        gemm_qkv_mfma2<<<dim3(N1_ / 128, M_ / 128), 256, 0, stream>>>(Xb, W1T, B1, Qw, Kw, Vw);
    } else {
        gemm_qkv_mfma<<<dim3(N1_ / 128, M_ / 128), 256, 0, stream>>>(X, W1T, B1, Qw, Kw, Vw);
    }
    attn_mfma<<<dim3(S_ / 128, B_ * NH_), 256, 0, stream>>>(Qw, Kw, Vw, Cw);
    conv_wT<<<dim3(H_ / 64, K_ / 64), 256, 0, stream>>>(W2, W2T, K_, H_);
    gemm_out_mfma<<<dim3(H_ / 128, M_ / 128), 256, 0, stream>>>(Cw, W2T, B2, OUT);
}